// Round 2
// baseline (1244.321 us; speedup 1.0000x reference)
//
#include <hip/hip_runtime.h>

#define NB 4
#define NN 4096
#define NT 16
#define NC 64
#define NE 32768

typedef unsigned int uint;
typedef unsigned short ushort;

__device__ inline ushort f2b(float f) {
  union { float f; uint u; } v; v.f = f;
  uint r = v.u + 0x7FFF + ((v.u >> 16) & 1);
  return (ushort)(r >> 16);
}
__device__ inline float blo(uint u) { union { uint i; float f; } v; v.i = u << 16; return v.f; }
__device__ inline float bhi(uint u) { union { uint i; float f; } v; v.i = u & 0xffff0000u; return v.f; }

// ---------------- tiny prep kernels ----------------

__global__ void k_zero(float* chan, int* count) {
  int i = blockIdx.x * blockDim.x + threadIdx.x;
  int stride = gridDim.x * blockDim.x;
  for (int idx = i; idx < NN; idx += stride) count[idx] = 0;
  for (int idx = i; idx < 128; idx += stride) chan[idx] = 0.f;
}

// Wt layout: float4 array, Wt4[(k*16+cq)*128 + o] = W[o, ci=4cq..4cq+3, k]
// WgT[c*64 + d] = Wg[d*64 + c]
__global__ void k_prep(const float* __restrict__ W1, const float* __restrict__ W2,
                       const float* __restrict__ Wg,
                       float* __restrict__ Wt1, float* __restrict__ Wt2,
                       float* __restrict__ WgT) {
  int i = blockIdx.x * blockDim.x + threadIdx.x;
  if (i < 24576) {
    int r = i & 3, o = (i >> 2) & 127, rowid = i >> 9;
    int k = rowid / 16, cq = rowid % 16, ci = cq * 4 + r;
    Wt1[i] = W1[o * 192 + ci * 3 + k];
    Wt2[i] = W2[o * 192 + ci * 3 + k];
  } else if (i < 24576 + 4096) {
    int j = i - 24576;
    int c = j >> 6, d = j & 63;
    WgT[j] = Wg[d * 64 + c];
  }
}

__global__ void k_count(const int* __restrict__ src, int* __restrict__ count) {
  int e = blockIdx.x * blockDim.x + threadIdx.x;
  if (e < NE) atomicAdd(&count[src[e]], 1);
}

__global__ void k_scan(const int* __restrict__ count, int* __restrict__ offsets,
                       int* __restrict__ cursor) {
  __shared__ int part[256];
  int tid = threadIdx.x;
  int base = tid * 16;
  int s = 0;
  for (int i = 0; i < 16; ++i) s += count[base + i];
  part[tid] = s;
  __syncthreads();
  if (tid == 0) {
    int r = 0;
    for (int i = 0; i < 256; ++i) { int t = part[i]; part[i] = r; r += t; }
    offsets[NN] = r;
  }
  __syncthreads();
  int r = part[tid];
  for (int i = 0; i < 16; ++i) {
    offsets[base + i] = r;
    cursor[base + i] = r;
    r += count[base + i];
  }
}

__global__ void k_place(const int* __restrict__ src, int* __restrict__ cursor,
                        int* __restrict__ esort) {
  int e = blockIdx.x * blockDim.x + threadIdx.x;
  if (e < NE) {
    int p = atomicAdd(&cursor[src[e]], 1);
    esort[p] = e;
  }
}

// ---------------- GLU1 + ReLU + GCN-linear, fused per (b,n) tile ----------------
// writes y (bf16) in NODE-MAJOR layout: y[((n*NB + b)*NT + t)*NC + d]
__global__ __launch_bounds__(256) void k_glu1lin(
    const float* __restrict__ x, const float* __restrict__ Wt1,
    const float* __restrict__ b1, const float* __restrict__ WgT,
    const float* __restrict__ bg, ushort* __restrict__ y) {
  __shared__ float xs[18 * 64];   // conv-padded tile, rows 0 and 17 are zero
  __shared__ float hs[16 * 64];   // GLU output tile
  int tid = threadIdx.x;
  int bn = blockIdx.x;            // b*NN + n
  int n = bn & (NN - 1);
  int b = bn >> 12;

  {
    float4 v = ((const float4*)(x + (size_t)bn * 1024))[tid];
    int f = tid * 4, t = f >> 6, c = f & 63;
    *(float4*)&xs[(t + 1) * 64 + c] = v;
    if (tid < 32) {
      int row = (tid >> 4) ? 17 : 0;
      *(float4*)&xs[row * 64 + (tid & 15) * 4] = make_float4(0, 0, 0, 0);
    }
  }
  __syncthreads();

  int o = tid & 63, tg = tid >> 6;
  float av[4] = {0, 0, 0, 0}, ag[4] = {0, 0, 0, 0};
  const float4* Wt4 = (const float4*)Wt1;
  const float4* xs4 = (const float4*)xs;
  #pragma unroll
  for (int k = 0; k < 3; ++k)
    for (int cq = 0; cq < 16; ++cq) {
      float4 wv = Wt4[(k * 16 + cq) * 128 + o];
      float4 wg = Wt4[(k * 16 + cq) * 128 + o + 64];
      #pragma unroll
      for (int j = 0; j < 4; ++j) {
        float4 xv = xs4[(tg * 4 + j + k) * 16 + cq];
        av[j] += xv.x * wv.x + xv.y * wv.y + xv.z * wv.z + xv.w * wv.w;
        ag[j] += xv.x * wg.x + xv.y * wg.y + xv.z * wg.z + xv.w * wg.w;
      }
    }
  float bv = b1[o], bgate = b1[o + 64];
  #pragma unroll
  for (int j = 0; j < 4; ++j) {
    float v = av[j] + bv, g = ag[j] + bgate;
    float h = v / (1.f + __expf(-g));
    hs[(tg * 4 + j) * 64 + o] = fmaxf(h, 0.f);
  }
  __syncthreads();

  // linear: y[t][d] = bg[d] + sum_c hs[t][c] * Wg[d][c]
  int t = tid >> 4, dq = tid & 15;
  const float4* WgT4 = (const float4*)WgT;
  float4 acc = *(const float4*)&bg[dq * 4];
  for (int c = 0; c < 64; ++c) {
    float xv = hs[t * 64 + c];
    float4 w = WgT4[c * 16 + dq];
    acc.x += xv * w.x; acc.y += xv * w.y; acc.z += xv * w.z; acc.w += xv * w.w;
  }
  ushort* ydst = y + ((size_t)n * NB + b) * 1024;
  ushort4 pv;
  pv.x = f2b(acc.x); pv.y = f2b(acc.y); pv.z = f2b(acc.z); pv.w = f2b(acc.w);
  *(ushort4*)&ydst[(t * 16 + dq) * 4] = pv;
}

// ---------------- CSR gather (weighted sum over edges) + ReLU, bf16 ----------------
// grid: NN * 2 blocks; block (n, s) covers elems [s*2048, s*2048+2048) of node n
__global__ __launch_bounds__(256) void k_gather(
    const ushort* __restrict__ y, const int* __restrict__ offsets,
    const int* __restrict__ esort, const int* __restrict__ edge_dst,
    const float* __restrict__ ew, ushort* __restrict__ agg) {
  int tid = threadIdx.x;
  int blk = blockIdx.x;
  int n = blk >> 1, s = blk & 1;
  int base = s * 2048 + tid * 8;   // elem offset within node's 4096
  int e0 = offsets[n], e1 = offsets[n + 1];

  float a0 = 0, a1 = 0, a2 = 0, a3 = 0, a4 = 0, a5 = 0, a6 = 0, a7 = 0;
  int e = e0;
  for (; e + 2 <= e1; e += 2) {
    int eid0 = esort[e], eid1 = esort[e + 1];
    int d0 = edge_dst[eid0], d1 = edge_dst[eid1];
    float w0 = ew[eid0], w1 = ew[eid1];
    uint4 v0 = *(const uint4*)(y + (size_t)d0 * 4096 + base);
    uint4 v1 = *(const uint4*)(y + (size_t)d1 * 4096 + base);
    a0 += w0 * blo(v0.x); a1 += w0 * bhi(v0.x);
    a2 += w0 * blo(v0.y); a3 += w0 * bhi(v0.y);
    a4 += w0 * blo(v0.z); a5 += w0 * bhi(v0.z);
    a6 += w0 * blo(v0.w); a7 += w0 * bhi(v0.w);
    a0 += w1 * blo(v1.x); a1 += w1 * bhi(v1.x);
    a2 += w1 * blo(v1.y); a3 += w1 * bhi(v1.y);
    a4 += w1 * blo(v1.z); a5 += w1 * bhi(v1.z);
    a6 += w1 * blo(v1.w); a7 += w1 * bhi(v1.w);
  }
  if (e < e1) {
    int eid0 = esort[e];
    int d0 = edge_dst[eid0];
    float w0 = ew[eid0];
    uint4 v0 = *(const uint4*)(y + (size_t)d0 * 4096 + base);
    a0 += w0 * blo(v0.x); a1 += w0 * bhi(v0.x);
    a2 += w0 * blo(v0.y); a3 += w0 * bhi(v0.y);
    a4 += w0 * blo(v0.z); a5 += w0 * bhi(v0.z);
    a6 += w0 * blo(v0.w); a7 += w0 * bhi(v0.w);
  }
  uint4 o;
  o.x = (uint)f2b(fmaxf(a0, 0.f)) | ((uint)f2b(fmaxf(a1, 0.f)) << 16);
  o.y = (uint)f2b(fmaxf(a2, 0.f)) | ((uint)f2b(fmaxf(a3, 0.f)) << 16);
  o.z = (uint)f2b(fmaxf(a4, 0.f)) | ((uint)f2b(fmaxf(a5, 0.f)) << 16);
  o.w = (uint)f2b(fmaxf(a6, 0.f)) | ((uint)f2b(fmaxf(a7, 0.f)) << 16);
  *(uint4*)(agg + (size_t)n * 4096 + base) = o;
}

// ---------------- GLU2 + residual + stats, per (b,n) tile ----------------
__global__ __launch_bounds__(256) void k_glu2(
    const ushort* __restrict__ agg, const float* __restrict__ x,
    const float* __restrict__ Wt2, const float* __restrict__ b2,
    float* __restrict__ out, float* __restrict__ chan) {
  __shared__ float xs[18 * 64];
  __shared__ float red[8 * 64];
  int tid = threadIdx.x;
  int bn = blockIdx.x;
  int n = bn & (NN - 1);
  int b = bn >> 12;

  {
    const uint2* a2 = (const uint2*)(agg + ((size_t)n * NB + b) * 1024);
    uint2 v = a2[tid];
    int f = tid * 4, t = f >> 6, c = f & 63;
    float* dst = &xs[(t + 1) * 64 + c];
    dst[0] = blo(v.x); dst[1] = bhi(v.x); dst[2] = blo(v.y); dst[3] = bhi(v.y);
    if (tid < 32) {
      int row = (tid >> 4) ? 17 : 0;
      *(float4*)&xs[row * 64 + (tid & 15) * 4] = make_float4(0, 0, 0, 0);
    }
  }
  __syncthreads();

  int o = tid & 63, tg = tid >> 6;
  float av[4] = {0, 0, 0, 0}, ag[4] = {0, 0, 0, 0};
  const float4* Wt4 = (const float4*)Wt2;
  const float4* xs4 = (const float4*)xs;
  #pragma unroll
  for (int k = 0; k < 3; ++k)
    for (int cq = 0; cq < 16; ++cq) {
      float4 wv = Wt4[(k * 16 + cq) * 128 + o];
      float4 wg = Wt4[(k * 16 + cq) * 128 + o + 64];
      #pragma unroll
      for (int j = 0; j < 4; ++j) {
        float4 xv = xs4[(tg * 4 + j + k) * 16 + cq];
        av[j] += xv.x * wv.x + xv.y * wv.y + xv.z * wv.z + xv.w * wv.w;
        ag[j] += xv.x * wg.x + xv.y * wg.y + xv.z * wg.z + xv.w * wg.w;
      }
    }
  float bv = b2[o], bgate = b2[o + 64];
  float ls1 = 0.f, ls2 = 0.f;
  #pragma unroll
  for (int j = 0; j < 4; ++j) {
    int t = tg * 4 + j;
    float v = av[j] + bv, g = ag[j] + bgate;
    float h = v / (1.f + __expf(-g));
    size_t idx = (((size_t)b * NN + n) * 16 + t) * 64 + o;
    float res = h + x[idx];
    out[idx] = res;
    ls1 += res; ls2 += res * res;
  }
  red[(tg * 2 + 0) * 64 + o] = ls1;
  red[(tg * 2 + 1) * 64 + o] = ls2;
  __syncthreads();
  if (tid < 64) {
    float s = red[0 * 64 + tid] + red[2 * 64 + tid] + red[4 * 64 + tid] + red[6 * 64 + tid];
    atomicAdd(&chan[tid], s);
  } else if (tid < 128) {
    int c = tid - 64;
    float s = red[1 * 64 + c] + red[3 * 64 + c] + red[5 * 64 + c] + red[7 * 64 + c];
    atomicAdd(&chan[64 + c], s);
  }
}

// ---------------- layernorm (global per-channel stats) + relu, in place ----------------
__global__ __launch_bounds__(256) void k_norm(
    float* __restrict__ out, const float* __restrict__ chan,
    const float* __restrict__ gamma, const float* __restrict__ beta) {
  __shared__ float sc[64], sh[64];
  int tid = threadIdx.x;
  if (tid < 64) {
    const float inv = 1.f / (float)(NB * NN * NT);
    float mean = chan[tid] * inv;
    float var = chan[64 + tid] * inv - mean * mean;
    float s = rsqrtf(var + 1e-5f) * gamma[tid];
    sc[tid] = s;
    sh[tid] = beta[tid] - mean * s;
  }
  __syncthreads();
  float4* o4 = (float4*)out;
  const int total = NB * NN * NT * 16;  // float4 count
  for (int i = blockIdx.x * blockDim.x + threadIdx.x; i < total;
       i += gridDim.x * blockDim.x) {
    float4 v = o4[i];
    int c = (i * 4) & 63;
    v.x = fmaxf(v.x * sc[c + 0] + sh[c + 0], 0.f);
    v.y = fmaxf(v.y * sc[c + 1] + sh[c + 1], 0.f);
    v.z = fmaxf(v.z * sc[c + 2] + sh[c + 2], 0.f);
    v.w = fmaxf(v.w * sc[c + 3] + sh[c + 3], 0.f);
    o4[i] = v;
  }
}

// ---------------- launch ----------------

extern "C" void kernel_launch(void* const* d_in, const int* in_sizes, int n_in,
                              void* d_out, int out_size, void* d_ws, size_t ws_size,
                              hipStream_t stream) {
  const float* x    = (const float*)d_in[0];
  const int* esrc   = (const int*)d_in[1];
  const int* edst   = (const int*)d_in[2];
  const float* ew   = (const float*)d_in[3];
  const float* W1   = (const float*)d_in[4];
  const float* b1   = (const float*)d_in[5];
  const float* Wg   = (const float*)d_in[6];
  const float* bg   = (const float*)d_in[7];
  const float* W2   = (const float*)d_in[8];
  const float* b2   = (const float*)d_in[9];
  const float* gamma = (const float*)d_in[10];
  const float* beta  = (const float*)d_in[11];
  float* out = (float*)d_out;

  ushort* y_bf   = (ushort*)d_ws;          // 16777216 bf16 (node-major)
  ushort* agg_bf = y_bf + 16777216;        // 16777216 bf16 (node-major)
  float* Wt1  = (float*)(agg_bf + 16777216);  // 24576
  float* Wt2  = Wt1 + 24576;               // 24576
  float* WgT  = Wt2 + 24576;               // 4096
  float* chan = WgT + 4096;                // 128
  int* count   = (int*)(chan + 128);       // 4096
  int* offsets = count + 4096;             // 4097
  int* cursor  = offsets + 4097;           // 4096
  int* esort   = cursor + 4096;            // 32768

  hipLaunchKernelGGL(k_zero, dim3(32), dim3(256), 0, stream, chan, count);
  hipLaunchKernelGGL(k_prep, dim3(112), dim3(256), 0, stream, W1, W2, Wg, Wt1, Wt2, WgT);
  hipLaunchKernelGGL(k_count, dim3(128), dim3(256), 0, stream, esrc, count);
  hipLaunchKernelGGL(k_scan, dim3(1), dim3(256), 0, stream, count, offsets, cursor);
  hipLaunchKernelGGL(k_place, dim3(128), dim3(256), 0, stream, esrc, cursor, esort);
  hipLaunchKernelGGL(k_glu1lin, dim3(NB * NN), dim3(256), 0, stream,
                     x, Wt1, b1, WgT, bg, y_bf);
  hipLaunchKernelGGL(k_gather, dim3(NN * 2), dim3(256), 0, stream,
                     y_bf, offsets, esort, edst, ew, agg_bf);
  hipLaunchKernelGGL(k_glu2, dim3(NB * NN), dim3(256), 0, stream,
                     agg_bf, x, Wt2, b2, out, chan);
  hipLaunchKernelGGL(k_norm, dim3(2048), dim3(256), 0, stream,
                     out, chan, gamma, beta);
}

// Round 3
// 566.443 us; speedup vs baseline: 2.1967x; 2.1967x over previous
//
#include <hip/hip_runtime.h>

#define NB 4
#define NN 4096
#define NT 16
#define NC 64
#define NE 32768

typedef unsigned int uint;
typedef unsigned short ushort;

__device__ inline ushort f2b(float f) {
  union { float f; uint u; } v; v.f = f;
  uint r = v.u + 0x7FFF + ((v.u >> 16) & 1);
  return (ushort)(r >> 16);
}
__device__ inline float blo(uint u) { union { uint i; float f; } v; v.i = u << 16; return v.f; }
__device__ inline float bhi(uint u) { union { uint i; float f; } v; v.i = u & 0xffff0000u; return v.f; }

// ---------------- tiny prep kernels ----------------

__global__ void k_zero(int* count) {
  int i = blockIdx.x * blockDim.x + threadIdx.x;
  if (i < NN) count[i] = 0;
}

// Wt layout: float4 array, Wt4[(k*16+cq)*128 + o] = W[o, ci=4cq..4cq+3, k]
// WgT[c*64 + d] = Wg[d*64 + c]
__global__ void k_prep(const float* __restrict__ W1, const float* __restrict__ W2,
                       const float* __restrict__ Wg,
                       float* __restrict__ Wt1, float* __restrict__ Wt2,
                       float* __restrict__ WgT) {
  int i = blockIdx.x * blockDim.x + threadIdx.x;
  if (i < 24576) {
    int r = i & 3, o = (i >> 2) & 127, rowid = i >> 9;
    int k = rowid / 16, cq = rowid % 16, ci = cq * 4 + r;
    Wt1[i] = W1[o * 192 + ci * 3 + k];
    Wt2[i] = W2[o * 192 + ci * 3 + k];
  } else if (i < 24576 + 4096) {
    int j = i - 24576;
    int c = j >> 6, d = j & 63;
    WgT[j] = Wg[d * 64 + c];
  }
}

__global__ void k_count(const int* __restrict__ src, int* __restrict__ count) {
  int e = blockIdx.x * blockDim.x + threadIdx.x;
  if (e < NE) atomicAdd(&count[src[e]], 1);
}

__global__ void k_scan(const int* __restrict__ count, int* __restrict__ offsets,
                       int* __restrict__ cursor) {
  __shared__ int part[256];
  int tid = threadIdx.x;
  int base = tid * 16;
  int s = 0;
  for (int i = 0; i < 16; ++i) s += count[base + i];
  part[tid] = s;
  __syncthreads();
  if (tid == 0) {
    int r = 0;
    for (int i = 0; i < 256; ++i) { int t = part[i]; part[i] = r; r += t; }
    offsets[NN] = r;
  }
  __syncthreads();
  int r = part[tid];
  for (int i = 0; i < 16; ++i) {
    offsets[base + i] = r;
    cursor[base + i] = r;
    r += count[base + i];
  }
}

__global__ void k_place(const int* __restrict__ src, int* __restrict__ cursor,
                        int* __restrict__ esort) {
  int e = blockIdx.x * blockDim.x + threadIdx.x;
  if (e < NE) {
    int p = atomicAdd(&cursor[src[e]], 1);
    esort[p] = e;
  }
}

// ---------------- GLU1 + ReLU + GCN-linear: one block per node, all 4 batches ----------------
// writes y (bf16) node-major: y[((n*NB + b)*NT + t)*NC + c]
#define HS_LD 68
__global__ __launch_bounds__(256, 4) void k_glu1lin(
    const float* __restrict__ x, const float* __restrict__ Wt1,
    const float* __restrict__ b1, const float* __restrict__ WgT,
    const float* __restrict__ bg, ushort* __restrict__ y) {
  __shared__ float xs[4][18 * 64];
  __shared__ float hs[4][16 * HS_LD];
  int tid = threadIdx.x;
  int n = blockIdx.x;

  #pragma unroll
  for (int q = 0; q < 4; ++q) {
    int f4 = q * 256 + tid;          // float4 index over 4 tiles
    int b = f4 >> 8, r = f4 & 255;
    float4 v = ((const float4*)(x + ((size_t)b * NN + n) * 1024))[r];
    int t = r >> 4, c = (r & 15) * 4;
    *(float4*)&xs[b][(t + 1) * 64 + c] = v;
  }
  if (tid < 128) {
    int b = tid >> 5, w = tid & 31;
    int row = (w >> 4) ? 17 : 0, c4 = w & 15;
    *(float4*)&xs[b][row * 64 + c4 * 4] = make_float4(0, 0, 0, 0);
  }
  __syncthreads();

  int o = tid & 63, tg = tid >> 6;
  float av[16], ag[16];
  #pragma unroll
  for (int i = 0; i < 16; ++i) { av[i] = 0.f; ag[i] = 0.f; }
  const float4* Wt4 = (const float4*)Wt1;
  #pragma unroll 2
  for (int kc = 0; kc < 48; ++kc) {
    float4 wv = Wt4[kc * 128 + o];
    float4 wg = Wt4[kc * 128 + o + 64];
    int k = kc >> 4, cq = kc & 15;
    #pragma unroll
    for (int b = 0; b < 4; ++b)
      #pragma unroll
      for (int j = 0; j < 4; ++j) {
        float4 xv = *(const float4*)&xs[b][(tg * 4 + j + k) * 64 + cq * 4];
        av[b * 4 + j] += xv.x * wv.x + xv.y * wv.y + xv.z * wv.z + xv.w * wv.w;
        ag[b * 4 + j] += xv.x * wg.x + xv.y * wg.y + xv.z * wg.z + xv.w * wg.w;
      }
  }
  float bv = b1[o], bgate = b1[o + 64];
  #pragma unroll
  for (int b = 0; b < 4; ++b)
    #pragma unroll
    for (int j = 0; j < 4; ++j) {
      float v = av[b * 4 + j] + bv, g = ag[b * 4 + j] + bgate;
      float h = v / (1.f + __expf(-g));
      hs[b][(tg * 4 + j) * HS_LD + o] = fmaxf(h, 0.f);
    }
  __syncthreads();

  // linear: y[t][d] = bg[d] + sum_c hs[t][c] * Wg[d][c]
  int t = tid >> 4, dq = tid & 15;
  const float4* WgT4 = (const float4*)WgT;
  float4 bg4 = *(const float4*)&bg[dq * 4];
  #pragma unroll
  for (int b = 0; b < 4; ++b) {
    float4 acc = bg4;
    #pragma unroll 4
    for (int c = 0; c < 64; ++c) {
      float xv = hs[b][t * HS_LD + c];
      float4 w = WgT4[c * 16 + dq];
      acc.x += xv * w.x; acc.y += xv * w.y; acc.z += xv * w.z; acc.w += xv * w.w;
    }
    ushort4 pv;
    pv.x = f2b(acc.x); pv.y = f2b(acc.y); pv.z = f2b(acc.z); pv.w = f2b(acc.w);
    *(ushort4*)&y[(((size_t)n * NB + b) * 16 + t) * 64 + dq * 4] = pv;
  }
}

// ---------------- CSR gather (weighted sum over edges) + ReLU, bf16 ----------------
__global__ __launch_bounds__(256) void k_gather(
    const ushort* __restrict__ y, const int* __restrict__ offsets,
    const int* __restrict__ esort, const int* __restrict__ edge_dst,
    const float* __restrict__ ew, ushort* __restrict__ agg) {
  int tid = threadIdx.x;
  int blk = blockIdx.x;
  int n = blk >> 1, s = blk & 1;
  int base = s * 2048 + tid * 8;
  int e0 = offsets[n], e1 = offsets[n + 1];

  float a0 = 0, a1 = 0, a2 = 0, a3 = 0, a4 = 0, a5 = 0, a6 = 0, a7 = 0;
  int e = e0;
  for (; e + 2 <= e1; e += 2) {
    int eid0 = esort[e], eid1 = esort[e + 1];
    int d0 = edge_dst[eid0], d1 = edge_dst[eid1];
    float w0 = ew[eid0], w1 = ew[eid1];
    uint4 v0 = *(const uint4*)(y + (size_t)d0 * 4096 + base);
    uint4 v1 = *(const uint4*)(y + (size_t)d1 * 4096 + base);
    a0 += w0 * blo(v0.x); a1 += w0 * bhi(v0.x);
    a2 += w0 * blo(v0.y); a3 += w0 * bhi(v0.y);
    a4 += w0 * blo(v0.z); a5 += w0 * bhi(v0.z);
    a6 += w0 * blo(v0.w); a7 += w0 * bhi(v0.w);
    a0 += w1 * blo(v1.x); a1 += w1 * bhi(v1.x);
    a2 += w1 * blo(v1.y); a3 += w1 * bhi(v1.y);
    a4 += w1 * blo(v1.z); a5 += w1 * bhi(v1.z);
    a6 += w1 * blo(v1.w); a7 += w1 * bhi(v1.w);
  }
  if (e < e1) {
    int eid0 = esort[e];
    int d0 = edge_dst[eid0];
    float w0 = ew[eid0];
    uint4 v0 = *(const uint4*)(y + (size_t)d0 * 4096 + base);
    a0 += w0 * blo(v0.x); a1 += w0 * bhi(v0.x);
    a2 += w0 * blo(v0.y); a3 += w0 * bhi(v0.y);
    a4 += w0 * blo(v0.z); a5 += w0 * bhi(v0.z);
    a6 += w0 * blo(v0.w); a7 += w0 * bhi(v0.w);
  }
  uint4 o;
  o.x = (uint)f2b(fmaxf(a0, 0.f)) | ((uint)f2b(fmaxf(a1, 0.f)) << 16);
  o.y = (uint)f2b(fmaxf(a2, 0.f)) | ((uint)f2b(fmaxf(a3, 0.f)) << 16);
  o.z = (uint)f2b(fmaxf(a4, 0.f)) | ((uint)f2b(fmaxf(a5, 0.f)) << 16);
  o.w = (uint)f2b(fmaxf(a6, 0.f)) | ((uint)f2b(fmaxf(a7, 0.f)) << 16);
  *(uint4*)(agg + (size_t)n * 4096 + base) = o;
}

// ---------------- GLU2 + residual + per-block stats (NO atomics) ----------------
// one block per node, all 4 batches; partials[row][n], row<64 = sum(ch), row 64..127 = sumsq(ch)
__global__ __launch_bounds__(256, 4) void k_glu2(
    const ushort* __restrict__ agg, const float* __restrict__ x,
    const float* __restrict__ Wt2, const float* __restrict__ b2,
    float* __restrict__ out, float* __restrict__ partials) {
  __shared__ float xs[4][18 * 64];
  __shared__ float red[8][64];
  int tid = threadIdx.x;
  int n = blockIdx.x;

  #pragma unroll
  for (int q = 0; q < 2; ++q) {
    int u = q * 256 + tid;                 // uint4 index over node's 4096 bf16
    uint4 v = ((const uint4*)(agg + (size_t)n * 4096))[u];
    int b = u >> 7, e = (u * 8) & 1023;
    int t = e >> 6, c = e & 63;
    float* dst = &xs[b][(t + 1) * 64 + c];
    dst[0] = blo(v.x); dst[1] = bhi(v.x);
    dst[2] = blo(v.y); dst[3] = bhi(v.y);
    dst[4] = blo(v.z); dst[5] = bhi(v.z);
    dst[6] = blo(v.w); dst[7] = bhi(v.w);
  }
  if (tid < 128) {
    int b = tid >> 5, w = tid & 31;
    int row = (w >> 4) ? 17 : 0, c4 = w & 15;
    *(float4*)&xs[b][row * 64 + c4 * 4] = make_float4(0, 0, 0, 0);
  }
  __syncthreads();

  int o = tid & 63, tg = tid >> 6;
  float av[16], ag[16];
  #pragma unroll
  for (int i = 0; i < 16; ++i) { av[i] = 0.f; ag[i] = 0.f; }
  const float4* Wt4 = (const float4*)Wt2;
  #pragma unroll 2
  for (int kc = 0; kc < 48; ++kc) {
    float4 wv = Wt4[kc * 128 + o];
    float4 wg = Wt4[kc * 128 + o + 64];
    int k = kc >> 4, cq = kc & 15;
    #pragma unroll
    for (int b = 0; b < 4; ++b)
      #pragma unroll
      for (int j = 0; j < 4; ++j) {
        float4 xv = *(const float4*)&xs[b][(tg * 4 + j + k) * 64 + cq * 4];
        av[b * 4 + j] += xv.x * wv.x + xv.y * wv.y + xv.z * wv.z + xv.w * wv.w;
        ag[b * 4 + j] += xv.x * wg.x + xv.y * wg.y + xv.z * wg.z + xv.w * wg.w;
      }
  }
  float bv = b2[o], bgate = b2[o + 64];
  float ls1 = 0.f, ls2 = 0.f;
  #pragma unroll
  for (int b = 0; b < 4; ++b)
    #pragma unroll
    for (int j = 0; j < 4; ++j) {
      int t = tg * 4 + j;
      float v = av[b * 4 + j] + bv, g = ag[b * 4 + j] + bgate;
      float h = v / (1.f + __expf(-g));
      int idx = ((b * NN + n) * 16 + t) * 64 + o;
      float res = h + x[idx];
      out[idx] = res;
      ls1 += res; ls2 += res * res;
    }
  red[tg * 2 + 0][o] = ls1;
  red[tg * 2 + 1][o] = ls2;
  __syncthreads();
  if (tid < 64) {
    partials[tid * NN + n] = red[0][tid] + red[2][tid] + red[4][tid] + red[6][tid];
  } else if (tid < 128) {
    int c = tid - 64;
    partials[tid * NN + n] = red[1][c] + red[3][c] + red[5][c] + red[7][c];
  }
}

// ---------------- reduce partials -> chan[128] ----------------
__global__ __launch_bounds__(256) void k_reduce(const float* __restrict__ partials,
                                                float* __restrict__ chan) {
  __shared__ float sm[256];
  int r = blockIdx.x, tid = threadIdx.x;
  const float* p = partials + (size_t)r * NN;
  float s = 0.f;
  for (int i = tid; i < NN; i += 256) s += p[i];
  sm[tid] = s;
  __syncthreads();
  for (int w = 128; w >= 1; w >>= 1) {
    if (tid < w) sm[tid] += sm[tid + w];
    __syncthreads();
  }
  if (tid == 0) chan[r] = sm[0];
}

// ---------------- layernorm (global per-channel stats) + relu, in place ----------------
__global__ __launch_bounds__(256) void k_norm(
    float* __restrict__ out, const float* __restrict__ chan,
    const float* __restrict__ gamma, const float* __restrict__ beta) {
  __shared__ float sc[64], sh[64];
  int tid = threadIdx.x;
  if (tid < 64) {
    const float inv = 1.f / (float)(NB * NN * NT);
    float mean = chan[tid] * inv;
    float var = chan[64 + tid] * inv - mean * mean;
    float s = rsqrtf(var + 1e-5f) * gamma[tid];
    sc[tid] = s;
    sh[tid] = beta[tid] - mean * s;
  }
  __syncthreads();
  float4* o4 = (float4*)out;
  const int total = NB * NN * NT * 16;
  for (int i = blockIdx.x * blockDim.x + threadIdx.x; i < total;
       i += gridDim.x * blockDim.x) {
    float4 v = o4[i];
    int c = (i * 4) & 63;
    v.x = fmaxf(v.x * sc[c + 0] + sh[c + 0], 0.f);
    v.y = fmaxf(v.y * sc[c + 1] + sh[c + 1], 0.f);
    v.z = fmaxf(v.z * sc[c + 2] + sh[c + 2], 0.f);
    v.w = fmaxf(v.w * sc[c + 3] + sh[c + 3], 0.f);
    o4[i] = v;
  }
}

// ---------------- launch ----------------

extern "C" void kernel_launch(void* const* d_in, const int* in_sizes, int n_in,
                              void* d_out, int out_size, void* d_ws, size_t ws_size,
                              hipStream_t stream) {
  const float* x    = (const float*)d_in[0];
  const int* esrc   = (const int*)d_in[1];
  const int* edst   = (const int*)d_in[2];
  const float* ew   = (const float*)d_in[3];
  const float* W1   = (const float*)d_in[4];
  const float* b1   = (const float*)d_in[5];
  const float* Wg   = (const float*)d_in[6];
  const float* bg   = (const float*)d_in[7];
  const float* W2   = (const float*)d_in[8];
  const float* b2   = (const float*)d_in[9];
  const float* gamma = (const float*)d_in[10];
  const float* beta  = (const float*)d_in[11];
  float* out = (float*)d_out;

  ushort* y_bf   = (ushort*)d_ws;          // 16777216 bf16 (node-major); dead after gather
  ushort* agg_bf = y_bf + 16777216;        // 16777216 bf16 (node-major)
  float* Wt1  = (float*)(agg_bf + 16777216);  // 24576
  float* Wt2  = Wt1 + 24576;               // 24576
  float* WgT  = Wt2 + 24576;               // 4096
  float* chan = WgT + 4096;                // 128
  int* count   = (int*)(chan + 128);       // 4096
  int* offsets = count + 4096;             // 4097
  int* cursor  = offsets + 4097;           // 4096
  int* esort   = cursor + 4096;            // 32768
  float* partials = (float*)y_bf;          // 128*4096 floats, aliases dead y

  hipLaunchKernelGGL(k_zero, dim3(16), dim3(256), 0, stream, count);
  hipLaunchKernelGGL(k_prep, dim3(112), dim3(256), 0, stream, W1, W2, Wg, Wt1, Wt2, WgT);
  hipLaunchKernelGGL(k_count, dim3(128), dim3(256), 0, stream, esrc, count);
  hipLaunchKernelGGL(k_scan, dim3(1), dim3(256), 0, stream, count, offsets, cursor);
  hipLaunchKernelGGL(k_place, dim3(128), dim3(256), 0, stream, esrc, cursor, esort);
  hipLaunchKernelGGL(k_glu1lin, dim3(NN), dim3(256), 0, stream,
                     x, Wt1, b1, WgT, bg, y_bf);
  hipLaunchKernelGGL(k_gather, dim3(NN * 2), dim3(256), 0, stream,
                     y_bf, offsets, esort, edst, ew, agg_bf);
  hipLaunchKernelGGL(k_glu2, dim3(NN), dim3(256), 0, stream,
                     agg_bf, x, Wt2, b2, out, partials);
  hipLaunchKernelGGL(k_reduce, dim3(128), dim3(256), 0, stream, partials, chan);
  hipLaunchKernelGGL(k_norm, dim3(2048), dim3(256), 0, stream,
                     out, chan, gamma, beta);
}

// Round 4
// 166.296 us; speedup vs baseline: 7.4826x; 3.4062x over previous
//
#include <hip/hip_runtime.h>

#define NB 4
#define NN 4096
#define NT 16
#define NC 64
#define NE 32768

typedef unsigned int uint;
typedef unsigned short ushort;

typedef short bf16x8 __attribute__((ext_vector_type(8)));
typedef float f32x4 __attribute__((ext_vector_type(4)));

union ABu { uint2 u2[2]; bf16x8 v; };

__device__ inline ushort f2b(float f) {
  union { float f; uint u; } v; v.f = f;
  uint r = v.u + 0x7FFF + ((v.u >> 16) & 1);
  return (ushort)(r >> 16);
}
__device__ inline float blo(uint u) { union { uint i; float f; } v; v.i = u << 16; return v.f; }
__device__ inline float bhi(uint u) { union { uint i; float f; } v; v.i = u & 0xffff0000u; return v.f; }

// ---------------- tiny prep kernels ----------------

__global__ void k_zero(int* count) {
  int i = blockIdx.x * blockDim.x + threadIdx.x;
  if (i < NN) count[i] = 0;
}

// Bpack fragment layout (bf16): Bp[(((s*8+nt)*64+l)*8)+j] = B[kappa][o]
//   kappa = 32s + 4*(l>>4) + (j&3) + 16*(j>>2), o = nt*16 + (l&15)
//   conv B: B[c + 64*kk][o] = W[o,c,kk];  linear B: B[c][d] = Wg[d,c]
__global__ void k_prep(const float* __restrict__ W1, const float* __restrict__ W2,
                       const float* __restrict__ Wg,
                       ushort* __restrict__ Bp1, ushort* __restrict__ Bp2,
                       ushort* __restrict__ Wgp) {
  int i = blockIdx.x * blockDim.x + threadIdx.x;
  if (i < 24576) {
    int j = i & 7, l = (i >> 3) & 63, nt = (i >> 9) & 7, s = i >> 12;
    int kap = 32 * s + 4 * (l >> 4) + (j & 3) + 16 * (j >> 2);
    int c = kap & 63, kk = kap >> 6, o = nt * 16 + (l & 15);
    Bp1[i] = f2b(W1[o * 192 + c * 3 + kk]);
    Bp2[i] = f2b(W2[o * 192 + c * 3 + kk]);
  } else if (i < 28672) {
    int i2 = i - 24576;
    int j = i2 & 7, l = (i2 >> 3) & 63, nt2 = (i2 >> 9) & 3, s2 = i2 >> 11;
    int kap = 32 * s2 + 4 * (l >> 4) + (j & 3) + 16 * (j >> 2);
    int d = nt2 * 16 + (l & 15);
    Wgp[i2] = f2b(Wg[d * 64 + kap]);
  }
}

__global__ void k_count(const int* __restrict__ src, int* __restrict__ count) {
  int e = blockIdx.x * blockDim.x + threadIdx.x;
  if (e < NE) atomicAdd(&count[src[e]], 1);
}

__global__ void k_scan(const int* __restrict__ count, int* __restrict__ offsets,
                       int* __restrict__ cursor) {
  __shared__ int part[256];
  int tid = threadIdx.x;
  int base = tid * 16;
  int s = 0;
  for (int i = 0; i < 16; ++i) s += count[base + i];
  part[tid] = s;
  __syncthreads();
  if (tid == 0) {
    int r = 0;
    for (int i = 0; i < 256; ++i) { int t = part[i]; part[i] = r; r += t; }
    offsets[NN] = r;
  }
  __syncthreads();
  int r = part[tid];
  for (int i = 0; i < 16; ++i) {
    offsets[base + i] = r;
    cursor[base + i] = r;
    r += count[base + i];
  }
}

__global__ void k_place(const int* __restrict__ src, int* __restrict__ cursor,
                        int* __restrict__ esort) {
  int e = blockIdx.x * blockDim.x + threadIdx.x;
  if (e < NE) {
    int p = atomicAdd(&cursor[src[e]], 1);
    esort[p] = e;
  }
}

// ---------------- GLU1(MFMA) + GCN-linear(MFMA): 1 node/block, 2 waves ----------------
// As[64][200] bf16: row r=(b*16+t), col kappa = c + 64*kk holds xpad[b][t+kk-1][c]
__global__ __launch_bounds__(128, 3) void k_glu1lin(
    const float* __restrict__ x, const ushort* __restrict__ Bp1,
    const float* __restrict__ b1, const ushort* __restrict__ Wgp,
    const float* __restrict__ bg, ushort* __restrict__ y) {
  __shared__ ushort As[64 * 200];
  int tid = threadIdx.x;
  int n = blockIdx.x;
  int w = tid >> 6, l = tid & 63, m = l & 15, g4 = l >> 4;

  // zero pad strips: row b*16 cols 0..63 (kk=0,t=-1), row b*16+15 cols 128..191 (kk=2,t=16)
  {
    int strip = tid >> 4, b = strip >> 1, half = strip & 1, c4 = (tid & 15) * 4;
    int idx = half ? ((b * 16 + 15) * 200 + 128 + c4) : (b * 16 * 200 + c4);
    *(uint2*)&As[idx] = make_uint2(0, 0);
  }
  // stage x -> As (bf16, conv-expanded)
  const float4* x4 = (const float4*)x;
  #pragma unroll
  for (int q = 0; q < 8; ++q) {
    int f4 = q * 128 + tid;
    int b = f4 >> 8, rem = f4 & 255, tau = rem >> 4, c4i = rem & 15;
    float4 v = x4[((b * NN + n) * 16 + tau) * 16 + c4i];
    uint2 p;
    p.x = (uint)f2b(v.x) | ((uint)f2b(v.y) << 16);
    p.y = (uint)f2b(v.z) | ((uint)f2b(v.w) << 16);
    int c0 = c4i * 4;
    #pragma unroll
    for (int kk = 0; kk < 3; ++kk) {
      int tp = tau + 1 - kk;
      if (tp >= 0 && tp < 16)
        *(uint2*)&As[(b * 16 + tp) * 200 + c0 + 64 * kk] = p;
    }
  }
  __syncthreads();

  // conv GEMM: wave w owns batches 2w, 2w+1
  f32x4 acc[2][8];
  #pragma unroll
  for (int bb = 0; bb < 2; ++bb)
    #pragma unroll
    for (int nt = 0; nt < 8; ++nt) {
      float bv = b1[nt * 16 + m];
      acc[bb][nt] = (f32x4){bv, bv, bv, bv};
    }
  int arow0 = (2 * w * 16 + m) * 200, arow1 = arow0 + 16 * 200;
  for (int s = 0; s < 6; ++s) {
    ABu a0, a1;
    int off = 32 * s + 4 * g4;
    a0.u2[0] = *(const uint2*)&As[arow0 + off];
    a0.u2[1] = *(const uint2*)&As[arow0 + off + 16];
    a1.u2[0] = *(const uint2*)&As[arow1 + off];
    a1.u2[1] = *(const uint2*)&As[arow1 + off + 16];
    #pragma unroll
    for (int nt = 0; nt < 8; ++nt) {
      bf16x8 bf = *(const bf16x8*)&Bp1[((s * 8 + nt) * 64 + l) * 8];
      acc[0][nt] = __builtin_amdgcn_mfma_f32_16x16x32_bf16(a0.v, bf, acc[0][nt], 0, 0, 0);
      acc[1][nt] = __builtin_amdgcn_mfma_f32_16x16x32_bf16(a1.v, bf, acc[1][nt], 0, 0, 0);
    }
  }
  __syncthreads();  // As dead below; reuse as hs

  // GLU epilogue -> hs (bf16) ; hs[b] at As + b*1088, row stride 68
  ushort* hs = As;
  #pragma unroll
  for (int bb = 0; bb < 2; ++bb) {
    int b = 2 * w + bb;
    #pragma unroll
    for (int nt = 0; nt < 4; ++nt)
      #pragma unroll
      for (int i = 0; i < 4; ++i) {
        float v = acc[bb][nt][i], gt = acc[bb][nt + 4][i];
        float h = fmaxf(v / (1.f + __expf(-gt)), 0.f);
        int t = 4 * g4 + i;
        hs[b * 1088 + t * 68 + nt * 16 + m] = f2b(h);
      }
  }

  // linear GEMM: y[t][d] = h @ Wg^T + bg (wave-private hs, no barrier needed)
  f32x4 acc2[2][4];
  #pragma unroll
  for (int bb = 0; bb < 2; ++bb)
    #pragma unroll
    for (int nt = 0; nt < 4; ++nt) {
      float bv = bg[nt * 16 + m];
      acc2[bb][nt] = (f32x4){bv, bv, bv, bv};
    }
  #pragma unroll
  for (int s2 = 0; s2 < 2; ++s2) {
    #pragma unroll
    for (int bb = 0; bb < 2; ++bb) {
      int b = 2 * w + bb;
      ABu a;
      int base = b * 1088 + m * 68 + 32 * s2 + 4 * g4;
      a.u2[0] = *(const uint2*)&hs[base];
      a.u2[1] = *(const uint2*)&hs[base + 16];
      #pragma unroll
      for (int nt = 0; nt < 4; ++nt) {
        bf16x8 bf = *(const bf16x8*)&Wgp[((s2 * 4 + nt) * 64 + l) * 8];
        acc2[bb][nt] = __builtin_amdgcn_mfma_f32_16x16x32_bf16(a.v, bf, acc2[bb][nt], 0, 0, 0);
      }
    }
  }
  // store y (bf16, node-major [n][b][t][c])
  #pragma unroll
  for (int bb = 0; bb < 2; ++bb) {
    int b = 2 * w + bb;
    ushort* yb = y + ((size_t)n * NB + b) * 1024;
    #pragma unroll
    for (int nt = 0; nt < 4; ++nt)
      #pragma unroll
      for (int i = 0; i < 4; ++i) {
        int t = 4 * g4 + i;
        yb[t * 64 + nt * 16 + m] = f2b(acc2[bb][nt][i]);
      }
  }
}

// ---------------- CSR gather (weighted sum over edges) + ReLU, bf16 ----------------
__global__ __launch_bounds__(256) void k_gather(
    const ushort* __restrict__ y, const int* __restrict__ offsets,
    const int* __restrict__ esort, const int* __restrict__ edge_dst,
    const float* __restrict__ ew, ushort* __restrict__ agg) {
  int tid = threadIdx.x;
  int blk = blockIdx.x;
  int n = blk >> 1, s = blk & 1;
  int base = s * 2048 + tid * 8;
  int e0 = offsets[n], e1 = offsets[n + 1];

  float a0 = 0, a1 = 0, a2 = 0, a3 = 0, a4 = 0, a5 = 0, a6 = 0, a7 = 0;
  int e = e0;
  for (; e + 2 <= e1; e += 2) {
    int eid0 = esort[e], eid1 = esort[e + 1];
    int d0 = edge_dst[eid0], d1 = edge_dst[eid1];
    float w0 = ew[eid0], w1 = ew[eid1];
    uint4 v0 = *(const uint4*)(y + (size_t)d0 * 4096 + base);
    uint4 v1 = *(const uint4*)(y + (size_t)d1 * 4096 + base);
    a0 += w0 * blo(v0.x); a1 += w0 * bhi(v0.x);
    a2 += w0 * blo(v0.y); a3 += w0 * bhi(v0.y);
    a4 += w0 * blo(v0.z); a5 += w0 * bhi(v0.z);
    a6 += w0 * blo(v0.w); a7 += w0 * bhi(v0.w);
    a0 += w1 * blo(v1.x); a1 += w1 * bhi(v1.x);
    a2 += w1 * blo(v1.y); a3 += w1 * bhi(v1.y);
    a4 += w1 * blo(v1.z); a5 += w1 * bhi(v1.z);
    a6 += w1 * blo(v1.w); a7 += w1 * bhi(v1.w);
  }
  if (e < e1) {
    int eid0 = esort[e];
    int d0 = edge_dst[eid0];
    float w0 = ew[eid0];
    uint4 v0 = *(const uint4*)(y + (size_t)d0 * 4096 + base);
    a0 += w0 * blo(v0.x); a1 += w0 * bhi(v0.x);
    a2 += w0 * blo(v0.y); a3 += w0 * bhi(v0.y);
    a4 += w0 * blo(v0.z); a5 += w0 * bhi(v0.z);
    a6 += w0 * blo(v0.w); a7 += w0 * bhi(v0.w);
  }
  uint4 o;
  o.x = (uint)f2b(fmaxf(a0, 0.f)) | ((uint)f2b(fmaxf(a1, 0.f)) << 16);
  o.y = (uint)f2b(fmaxf(a2, 0.f)) | ((uint)f2b(fmaxf(a3, 0.f)) << 16);
  o.z = (uint)f2b(fmaxf(a4, 0.f)) | ((uint)f2b(fmaxf(a5, 0.f)) << 16);
  o.w = (uint)f2b(fmaxf(a6, 0.f)) | ((uint)f2b(fmaxf(a7, 0.f)) << 16);
  *(uint4*)(agg + (size_t)n * 4096 + base) = o;
}

// ---------------- GLU2(MFMA) + residual + per-block stats ----------------
__global__ __launch_bounds__(128, 3) void k_glu2(
    const ushort* __restrict__ agg, const float* __restrict__ x,
    const ushort* __restrict__ Bp2, const float* __restrict__ b2,
    float* __restrict__ out, float* __restrict__ partials) {
  __shared__ ushort As[64 * 200];
  int tid = threadIdx.x;
  int n = blockIdx.x;
  int w = tid >> 6, l = tid & 63, m = l & 15, g4 = l >> 4;

  {
    int strip = tid >> 4, b = strip >> 1, half = strip & 1, c4 = (tid & 15) * 4;
    int idx = half ? ((b * 16 + 15) * 200 + 128 + c4) : (b * 16 * 200 + c4);
    *(uint2*)&As[idx] = make_uint2(0, 0);
  }
  const uint4* ag4 = (const uint4*)(agg + (size_t)n * 4096);
  #pragma unroll
  for (int q = 0; q < 4; ++q) {
    int u = q * 128 + tid;
    uint4 v = ag4[u];
    int b = u >> 7, rem = u & 127, tau = rem >> 3, c0 = (rem & 7) * 8;
    #pragma unroll
    for (int kk = 0; kk < 3; ++kk) {
      int tp = tau + 1 - kk;
      if (tp >= 0 && tp < 16)
        *(uint4*)&As[(b * 16 + tp) * 200 + c0 + 64 * kk] = v;
    }
  }
  __syncthreads();

  f32x4 acc[2][8];
  #pragma unroll
  for (int bb = 0; bb < 2; ++bb)
    #pragma unroll
    for (int nt = 0; nt < 8; ++nt) {
      float bv = b2[nt * 16 + m];
      acc[bb][nt] = (f32x4){bv, bv, bv, bv};
    }
  int arow0 = (2 * w * 16 + m) * 200, arow1 = arow0 + 16 * 200;
  for (int s = 0; s < 6; ++s) {
    ABu a0, a1;
    int off = 32 * s + 4 * g4;
    a0.u2[0] = *(const uint2*)&As[arow0 + off];
    a0.u2[1] = *(const uint2*)&As[arow0 + off + 16];
    a1.u2[0] = *(const uint2*)&As[arow1 + off];
    a1.u2[1] = *(const uint2*)&As[arow1 + off + 16];
    #pragma unroll
    for (int nt = 0; nt < 8; ++nt) {
      bf16x8 bf = *(const bf16x8*)&Bp2[((s * 8 + nt) * 64 + l) * 8];
      acc[0][nt] = __builtin_amdgcn_mfma_f32_16x16x32_bf16(a0.v, bf, acc[0][nt], 0, 0, 0);
      acc[1][nt] = __builtin_amdgcn_mfma_f32_16x16x32_bf16(a1.v, bf, acc[1][nt], 0, 0, 0);
    }
  }
  __syncthreads();  // As dead; reuse as float red[2][8][68]

  float* red = (float*)As;
  float p1[4] = {0, 0, 0, 0}, p2[4] = {0, 0, 0, 0};
  #pragma unroll
  for (int bb = 0; bb < 2; ++bb) {
    int b = 2 * w + bb;
    #pragma unroll
    for (int nt = 0; nt < 4; ++nt)
      #pragma unroll
      for (int i = 0; i < 4; ++i) {
        float v = acc[bb][nt][i], gt = acc[bb][nt + 4][i];
        float h = v / (1.f + __expf(-gt));
        int t = 4 * g4 + i;
        int idx = ((b * NN + n) * 16 + t) * 64 + nt * 16 + m;
        float res = h + x[idx];
        out[idx] = res;
        p1[nt] += res;
        p2[nt] += res * res;
      }
  }
  int rr = w * 4 + g4;
  #pragma unroll
  for (int nt = 0; nt < 4; ++nt) {
    red[rr * 68 + nt * 16 + m] = p1[nt];
    red[544 + rr * 68 + nt * 16 + m] = p2[nt];
  }
  __syncthreads();
  if (tid < 64) {
    float s = 0;
    #pragma unroll
    for (int r2 = 0; r2 < 8; ++r2) s += red[r2 * 68 + tid];
    partials[tid * NN + n] = s;
  } else if (tid < 128) {
    int c = tid - 64;
    float s = 0;
    #pragma unroll
    for (int r2 = 0; r2 < 8; ++r2) s += red[544 + r2 * 68 + c];
    partials[(64 + c) * NN + n] = s;
  }
}

// ---------------- reduce partials -> chan[128] ----------------
__global__ __launch_bounds__(256) void k_reduce(const float* __restrict__ partials,
                                                float* __restrict__ chan) {
  __shared__ float sm[256];
  int r = blockIdx.x, tid = threadIdx.x;
  const float* p = partials + (size_t)r * NN;
  float s = 0.f;
  for (int i = tid; i < NN; i += 256) s += p[i];
  sm[tid] = s;
  __syncthreads();
  for (int w = 128; w >= 1; w >>= 1) {
    if (tid < w) sm[tid] += sm[tid + w];
    __syncthreads();
  }
  if (tid == 0) chan[r] = sm[0];
}

// ---------------- layernorm (global per-channel stats) + relu, in place ----------------
__global__ __launch_bounds__(256) void k_norm(
    float* __restrict__ out, const float* __restrict__ chan,
    const float* __restrict__ gamma, const float* __restrict__ beta) {
  __shared__ float sc[64], sh[64];
  int tid = threadIdx.x;
  if (tid < 64) {
    const float inv = 1.f / (float)(NB * NN * NT);
    float mean = chan[tid] * inv;
    float var = chan[64 + tid] * inv - mean * mean;
    float s = rsqrtf(var + 1e-5f) * gamma[tid];
    sc[tid] = s;
    sh[tid] = beta[tid] - mean * s;
  }
  __syncthreads();
  float4* o4 = (float4*)out;
  const int total = NB * NN * NT * 16;
  for (int i = blockIdx.x * blockDim.x + threadIdx.x; i < total;
       i += gridDim.x * blockDim.x) {
    float4 v = o4[i];
    int c = (i * 4) & 63;
    v.x = fmaxf(v.x * sc[c + 0] + sh[c + 0], 0.f);
    v.y = fmaxf(v.y * sc[c + 1] + sh[c + 1], 0.f);
    v.z = fmaxf(v.z * sc[c + 2] + sh[c + 2], 0.f);
    v.w = fmaxf(v.w * sc[c + 3] + sh[c + 3], 0.f);
    o4[i] = v;
  }
}

// ---------------- launch ----------------

extern "C" void kernel_launch(void* const* d_in, const int* in_sizes, int n_in,
                              void* d_out, int out_size, void* d_ws, size_t ws_size,
                              hipStream_t stream) {
  const float* x    = (const float*)d_in[0];
  const int* esrc   = (const int*)d_in[1];
  const int* edst   = (const int*)d_in[2];
  const float* ew   = (const float*)d_in[3];
  const float* W1   = (const float*)d_in[4];
  const float* b1   = (const float*)d_in[5];
  const float* Wg   = (const float*)d_in[6];
  const float* bg   = (const float*)d_in[7];
  const float* W2   = (const float*)d_in[8];
  const float* b2   = (const float*)d_in[9];
  const float* gamma = (const float*)d_in[10];
  const float* beta  = (const float*)d_in[11];
  float* out = (float*)d_out;

  ushort* y_bf   = (ushort*)d_ws;          // 16777216 bf16 (node-major); dead after gather
  ushort* agg_bf = y_bf + 16777216;        // 16777216 bf16 (node-major)
  ushort* Bp1    = agg_bf + 16777216;      // 24576
  ushort* Bp2    = Bp1 + 24576;            // 24576
  ushort* Wgp    = Bp2 + 24576;            // 4096
  float* chan    = (float*)(Wgp + 4096);   // 128
  int* count   = (int*)(chan + 128);       // 4096
  int* offsets = count + 4096;             // 4097
  int* cursor  = offsets + 4097;           // 4096
  int* esort   = cursor + 4096;            // 32768
  float* partials = (float*)y_bf;          // 128*4096 floats, aliases dead y

  hipLaunchKernelGGL(k_zero, dim3(16), dim3(256), 0, stream, count);
  hipLaunchKernelGGL(k_prep, dim3(112), dim3(256), 0, stream, W1, W2, Wg, Bp1, Bp2, Wgp);
  hipLaunchKernelGGL(k_count, dim3(128), dim3(256), 0, stream, esrc, count);
  hipLaunchKernelGGL(k_scan, dim3(1), dim3(256), 0, stream, count, offsets, cursor);
  hipLaunchKernelGGL(k_place, dim3(128), dim3(256), 0, stream, esrc, cursor, esort);
  hipLaunchKernelGGL(k_glu1lin, dim3(NN), dim3(128), 0, stream,
                     x, Bp1, b1, Wgp, bg, y_bf);
  hipLaunchKernelGGL(k_gather, dim3(NN * 2), dim3(256), 0, stream,
                     y_bf, offsets, esort, edst, ew, agg_bf);
  hipLaunchKernelGGL(k_glu2, dim3(NN), dim3(128), 0, stream,
                     agg_bf, x, Bp2, b2, out, partials);
  hipLaunchKernelGGL(k_reduce, dim3(128), dim3(256), 0, stream, partials, chan);
  hipLaunchKernelGGL(k_norm, dim3(2048), dim3(256), 0, stream,
                     out, chan, gamma, beta);
}